// Round 2
// baseline (108.628 us; speedup 1.0000x reference)
//
#include <hip/hip_runtime.h>
#include <cmath>

#define HH 512
#define WW 512
#define TILE 64
#define S_IMG 72    // staged image tile stride (72 rows x 72 cols)
#define S_BL  72    // blurred tile stride (68 rows used)
#define S_HB  68    // hblur / mag tile stride
#define NT 256

struct Blur5 { float w[5]; };

// packed (dr+1),(dc+1) 2-bit LUTs for the 8 NMS directions
// OFFS = {(0,1),(-1,1),(-1,0),(-1,-1),(0,-1),(1,-1),(1,0),(1,1)}
#define DR_PACK 43265u
#define DC_PACK 36890u

// rc = jnp.round((degrees(atan2(gy,gx)) + 180)/45) in [0,8], via comparisons.
__device__ __forceinline__ int orient_bin(float gx, float gy) {
  const float T1 = 0.41421356237309503f;  // tan(22.5 deg)
  const float T2 = 2.41421356237309503f;  // tan(67.5 deg)
  float a = fabsf(gy), b = fabsf(gx);
  int sx = (int)(__float_as_uint(gx) >> 31);
  int sy = (int)(__float_as_uint(gy) >> 31);
  int rc;
  if (a <= T1 * b)      rc = sx ? (8 - 8 * sy) : 4;   // near 0 / +-180
  else if (a >= T2 * b) rc = 6 - 4 * sy;              // near +-90
  else                  rc = sx ? (7 - 6 * sy) : (5 - 2 * sy);  // diagonals
  return rc;
}

template<bool INT>
__device__ __forceinline__ void canny_tile(
    const float* __restrict__ img, int base_r, int base_c,
    float* __restrict__ sA, float* __restrict__ sB, const Blur5& kb,
    float thin[16], int rcv[16])
{
  const int lane = threadIdx.x & 63;
  const int wv   = threadIdx.x >> 6;
  const float k0 = kb.w[0], k1 = kb.w[1], k2 = kb.w[2], k3 = kb.w[3], k4 = kb.w[4];

  // ---- P1: stage 72x72 (halo 4), zero outside image ----
  for (int r = wv; r < 72; r += 4) {
    int gr = base_r + r - 4;
    float v0 = 0.f, v1 = 0.f;
    if (INT) {
      const float* row = img + gr * WW + (base_c - 4);
      v0 = row[lane];
      if (lane < 8) v1 = row[64 + lane];
    } else {
      bool rok = (unsigned)gr < HH;
      int gc0 = base_c - 4 + lane;
      if (rok && (unsigned)gc0 < WW) v0 = img[gr * WW + gc0];
      if (lane < 8) {
        int gc1 = gc0 + 64;
        if (rok && (unsigned)gc1 < WW) v1 = img[gr * WW + gc1];
      }
    }
    sA[r * S_IMG + lane] = v0;
    if (lane < 8) sA[r * S_IMG + 64 + lane] = v1;
  }
  __syncthreads();

  // ---- P2: horizontal 5-tap blur -> sB [72][68] ----
  for (int r = wv; r < 72; r += 4) {
    const float* p = &sA[r * S_IMG];
    sB[r * S_HB + lane] =
        k0*p[lane] + k1*p[lane+1] + k2*p[lane+2] + k3*p[lane+3] + k4*p[lane+4];
    if (lane < 4) {
      int c = 64 + lane;
      sB[r * S_HB + c] =
          k0*p[c] + k1*p[c+1] + k2*p[c+2] + k3*p[c+3] + k4*p[c+4];
    }
  }
  __syncthreads();

  // ---- P3: vertical 5-tap blur -> sA [68 rows][stride 72]; zero outside ----
  for (int r = wv; r < 68; r += 4) {
    const float* p = &sB[r * S_HB];
    float v0 = k0*p[lane] + k1*p[lane+S_HB] + k2*p[lane+2*S_HB]
             + k3*p[lane+3*S_HB] + k4*p[lane+4*S_HB];
    float v1 = 0.f;
    if (lane < 4) {
      int c = 64 + lane;
      v1 = k0*p[c] + k1*p[c+S_HB] + k2*p[c+2*S_HB] + k3*p[c+3*S_HB] + k4*p[c+4*S_HB];
    }
    if (!INT) {
      int gr = base_r + r - 2;
      bool rok = (unsigned)gr < HH;
      int gc0 = base_c + lane - 2;
      if (!(rok && (unsigned)gc0 < WW)) v0 = 0.f;
      if (lane < 4) { int gc1 = gc0 + 64; if (!(rok && (unsigned)gc1 < WW)) v1 = 0.f; }
    }
    sA[r * S_BL + lane] = v0;
    if (lane < 4) sA[r * S_BL + 64 + lane] = v1;
  }
  __syncthreads();

  // ---- P4a: sobel magnitude -> sB [66 rows][stride 68]; zero outside ----
  for (int r = wv; r < 66; r += 4) {
    const float* p = &sA[r * S_BL];
    {
      int c = lane;
      float b00=p[c],        b01=p[c+1],          b02=p[c+2];
      float b10=p[c+S_BL],                        b12=p[c+S_BL+2];
      float b20=p[c+2*S_BL], b21=p[c+2*S_BL+1],   b22=p[c+2*S_BL+2];
      float gx=(b02-b00)+2.f*(b12-b10)+(b22-b20);
      float gy=(b20-b00)+2.f*(b21-b01)+(b22-b02);
      float m = sqrtf(gx*gx + gy*gy + 1e-12f);
      if (!INT) {
        int gr = base_r + r - 1, gc = base_c + c - 1;
        if (!((unsigned)gr < HH && (unsigned)gc < WW)) m = 0.f;
      }
      sB[r * S_HB + c] = m;
    }
    if (lane < 2) {
      int c = 64 + lane;
      float b00=p[c],        b01=p[c+1],          b02=p[c+2];
      float b10=p[c+S_BL],                        b12=p[c+S_BL+2];
      float b20=p[c+2*S_BL], b21=p[c+2*S_BL+1],   b22=p[c+2*S_BL+2];
      float gx=(b02-b00)+2.f*(b12-b10)+(b22-b20);
      float gy=(b20-b00)+2.f*(b21-b01)+(b22-b02);
      float m = sqrtf(gx*gx + gy*gy + 1e-12f);
      if (!INT) {
        int gr = base_r + r - 1, gc = base_c + c - 1;
        if (!((unsigned)gr < HH && (unsigned)gc < WW)) m = 0.f;
      }
      sB[r * S_HB + c] = m;
    }
  }
  __syncthreads();

  // ---- P4b+P5: per-center orientation bin + NMS ----
  #pragma unroll
  for (int i = 0; i < 16; ++i) {
    int r = (wv << 4) + i;
    const float* p = &sA[(r + 1) * S_BL + (lane + 1)];
    float b00=p[0],      b01=p[1],         b02=p[2];
    float b10=p[S_BL],                     b12=p[S_BL+2];
    float b20=p[2*S_BL], b21=p[2*S_BL+1],  b22=p[2*S_BL+2];
    float gx=(b02-b00)+2.f*(b12-b10)+(b22-b20);
    float gy=(b20-b00)+2.f*(b21-b01)+(b22-b02);
    int rc = orient_bin(gx, gy);
    rcv[i] = rc;
    int ip = rc & 7;
    int dr = (int)((DR_PACK >> (2 * ip)) & 3u) - 1;
    int dc = (int)((DC_PACK >> (2 * ip)) & 3u) - 1;
    const float* q = &sB[(r + 1) * S_HB + (lane + 1)];
    float mc = q[0];
    float n1 = q[dr * S_HB + dc];
    float n2 = q[-dr * S_HB - dc];
    thin[i] = (fminf(mc - n1, mc - n2) > 0.f) ? mc : 0.f;
  }
  __syncthreads();  // protect sA/sB before reuse
}

template<bool INT>
__device__ __forceinline__ float tile_loss(
    const float* __restrict__ xb, const float* __restrict__ yb,
    int base_r, int base_c, float* sA, float* sB, const Blur5& kb)
{
  float thin_x[16]; int rc_x[16];
  canny_tile<INT>(xb, base_r, base_c, sA, sB, kb, thin_x, rc_x);
  float thin_y[16]; int rc_y[16];
  canny_tile<INT>(yb, base_r, base_c, sA, sB, kb, thin_y, rc_y);

  float s = 0.f; int so = 0;
  #pragma unroll
  for (int i = 0; i < 16; ++i) {
    s += fabsf(thin_x[i] - thin_y[i]);
    so += abs(rc_x[i] - rc_y[i]);
  }
  return s + 45.f * (float)so;
}

__global__ void __launch_bounds__(NT)
canny_loss_kernel(const float* __restrict__ X, const float* __restrict__ Y,
                  float* __restrict__ out, Blur5 kb)
{
  __shared__ float sA[72 * S_IMG];
  __shared__ float sB[72 * S_HB];
  __shared__ float red[NT / 64];

  const int b = blockIdx.y;
  const int tr = (int)(blockIdx.x >> 3), tc = (int)(blockIdx.x & 7);
  const int base_r = tr * TILE, base_c = tc * TILE;
  const float* xb = X + (size_t)b * HH * WW;
  const float* yb = Y + (size_t)b * HH * WW;

  const bool interior = (tr >= 1) & (tr <= 6) & (tc >= 1) & (tc <= 6);
  float s = interior ? tile_loss<true >(xb, yb, base_r, base_c, sA, sB, kb)
                     : tile_loss<false>(xb, yb, base_r, base_c, sA, sB, kb);

  #pragma unroll
  for (int off = 32; off >= 1; off >>= 1) s += __shfl_down(s, off, 64);
  const int lane = threadIdx.x & 63, wv = threadIdx.x >> 6;
  if (lane == 0) red[wv] = s;
  __syncthreads();
  if (threadIdx.x == 0) {
    float t = red[0] + red[1] + red[2] + red[3];
    atomicAdd(out, t * (1.0f / ((float)HH * (float)WW)));
  }
}

extern "C" void kernel_launch(void* const* d_in, const int* in_sizes, int n_in,
                              void* d_out, int out_size, void* d_ws, size_t ws_size,
                              hipStream_t stream)
{
  const float* X = (const float*)d_in[0];
  const float* Y = (const float*)d_in[1];
  float* out = (float*)d_out;

  hipMemsetAsync(out, 0, (size_t)out_size * sizeof(float), stream);

  Blur5 kb;
  {
    double g[5], ssum = 0.0;
    for (int i = 0; i < 5; ++i) { double d = i - 2; g[i] = std::exp(-(d * d) / 2.0); ssum += g[i]; }
    for (int i = 0; i < 5; ++i) kb.w[i] = (float)(g[i] / ssum);
  }

  dim3 grid(64, 16);   // 8x8 tiles of 64x64, 16 batch
  canny_loss_kernel<<<grid, NT, 0, stream>>>(X, Y, out, kb);
}

// Round 3
// 57.805 us; speedup vs baseline: 1.8792x; 1.8792x over previous
//
#include <hip/hip_runtime.h>
#include <cmath>

#define HH 512
#define WW 512
#define TILE 64
#define IMG_T 72   // TILE + 2*4 halo (blur2 + sobel1 + nms1)
#define HB_W 68    // hblur cols = TILE + 2*2
#define BL_T 68    // blurred tile = TILE + 2*2
#define MAG_T 66   // mag tile = TILE + 2*1
#define NTHREADS 256

struct Blur5 { float w[5]; };

// packed (dr+1), (dc+1) 2-bit LUTs for the 8 NMS directions
// OFFS = {(0,1),(-1,1),(-1,0),(-1,-1),(0,-1),(1,-1),(1,0),(1,1)}
#define DR_PACK 43265u
#define DC_PACK 36890u

// rc = jnp.round((degrees(atan2(gy,gx)) + 180)/45) in [0,8], via comparisons.
// Validated vs reference in R1 (absmax 0.0).
__device__ __forceinline__ int orient_bin(float gx, float gy) {
  const float T1 = 0.41421356237309503f;  // tan(22.5 deg)
  const float T2 = 2.41421356237309503f;  // tan(67.5 deg)
  float a = fabsf(gy), b = fabsf(gx);
  int sx = (int)(__float_as_uint(gx) >> 31);
  int sy = (int)(__float_as_uint(gy) >> 31);
  int rc;
  if (a <= T1 * b)      rc = sx ? (8 - 8 * sy) : 4;   // near 0 / +-180
  else if (a >= T2 * b) rc = 6 - 4 * sy;              // near +-90
  else                  rc = sx ? (7 - 6 * sy) : (5 - 2 * sy);  // diagonals
  return rc;
}

__device__ __forceinline__ void canny_tile(
    const float* __restrict__ img, int base_r, int base_c,
    float* sA, float* sB, const Blur5& kb,
    float thin[16], int rcv[16])
{
  const int tid = threadIdx.x;

  // ---- Phase 1: stage img tile (+halo 4), zero padding outside image ----
  for (int idx = tid; idx < IMG_T * IMG_T; idx += NTHREADS) {
    int ir = idx / IMG_T, ic = idx - ir * IMG_T;
    int gr = base_r + ir - 4, gc = base_c + ic - 4;
    float v = 0.f;
    if ((unsigned)gr < HH && (unsigned)gc < WW) v = img[gr * WW + gc];
    sA[idx] = v;
  }
  __syncthreads();

  // ---- Phase 2: horizontal 5-tap blur -> sB [72][68] ----
  for (int idx = tid; idx < IMG_T * HB_W; idx += NTHREADS) {
    int r = idx / HB_W, c = idx - r * HB_W;
    const float* p = &sA[r * IMG_T + c];
    sB[idx] = kb.w[0]*p[0] + kb.w[1]*p[1] + kb.w[2]*p[2] + kb.w[3]*p[3] + kb.w[4]*p[4];
  }
  __syncthreads();

  // ---- Phase 3: vertical 5-tap blur -> sA [68][68]; zero outside image ----
  for (int idx = tid; idx < BL_T * BL_T; idx += NTHREADS) {
    int r = idx / BL_T, c = idx - r * BL_T;
    int gr = base_r + r - 2, gc = base_c + c - 2;
    float v = 0.f;
    if ((unsigned)gr < HH && (unsigned)gc < WW) {
      const float* p = &sB[r * HB_W + c];
      v = kb.w[0]*p[0] + kb.w[1]*p[HB_W] + kb.w[2]*p[2*HB_W]
        + kb.w[3]*p[3*HB_W] + kb.w[4]*p[4*HB_W];
    }
    sA[r * BL_T + c] = v;
  }
  __syncthreads();

  // ---- Phase 4a: sobel magnitude -> sB [66][66]; zero outside image ----
  for (int idx = tid; idx < MAG_T * MAG_T; idx += NTHREADS) {
    int r = idx / MAG_T, c = idx - r * MAG_T;
    int gr = base_r + r - 1, gc = base_c + c - 1;
    float m = 0.f;
    if ((unsigned)gr < HH && (unsigned)gc < WW) {
      const float* p = &sA[r * BL_T + c];
      float b00 = p[0],        b01 = p[1],          b02 = p[2];
      float b10 = p[BL_T],                          b12 = p[BL_T + 2];
      float b20 = p[2*BL_T],   b21 = p[2*BL_T + 1], b22 = p[2*BL_T + 2];
      float gx = (b02 - b00) + 2.f*(b12 - b10) + (b22 - b20);
      float gy = (b20 - b00) + 2.f*(b21 - b01) + (b22 - b02);
      m = sqrtf(gx*gx + gy*gy + 1e-12f);
    }
    sB[r * MAG_T + c] = m;
  }

  // ---- Phase 4b: per-center-pixel orientation bin (registers) ----
  const int cc = tid & 63;
  const int r0 = (tid >> 6) * 16;
  #pragma unroll
  for (int i = 0; i < 16; ++i) {
    int r = r0 + i;
    const float* p = &sA[(r + 1) * BL_T + (cc + 1)];
    float b00 = p[0],        b01 = p[1],          b02 = p[2];
    float b10 = p[BL_T],                          b12 = p[BL_T + 2];
    float b20 = p[2*BL_T],   b21 = p[2*BL_T + 1], b22 = p[2*BL_T + 2];
    float gx = (b02 - b00) + 2.f*(b12 - b10) + (b22 - b20);
    float gy = (b20 - b00) + 2.f*(b21 - b01) + (b22 - b02);
    rcv[i] = orient_bin(gx, gy);
  }
  __syncthreads();

  // ---- Phase 5: NMS (directional neighbor diffs over zero-padded mag) ----
  #pragma unroll
  for (int i = 0; i < 16; ++i) {
    int r = r0 + i;
    int ip = rcv[i] & 7;
    int dr = (int)((DR_PACK >> (2 * ip)) & 3u) - 1;
    int dc = (int)((DC_PACK >> (2 * ip)) & 3u) - 1;
    float mc = sB[(r + 1) * MAG_T + (cc + 1)];
    float n1 = sB[(r + 1 + dr) * MAG_T + (cc + 1 + dc)];
    float n2 = sB[(r + 1 - dr) * MAG_T + (cc + 1 - dc)];
    float dp = mc - n1, dn = mc - n2;
    thin[i] = (fminf(dp, dn) > 0.f) ? mc : 0.f;
  }
  __syncthreads();
}

__global__ void __launch_bounds__(NTHREADS)
canny_loss_kernel(const float* __restrict__ X, const float* __restrict__ Y,
                  float* __restrict__ out, Blur5 kb)
{
  __shared__ float sA[IMG_T * IMG_T];
  __shared__ float sB[IMG_T * HB_W];
  __shared__ float red[NTHREADS / 64];

  const int b = blockIdx.y;
  const int base_r = (int)(blockIdx.x >> 3) * TILE;
  const int base_c = (int)(blockIdx.x & 7) * TILE;
  const float* xb = X + (size_t)b * HH * WW;
  const float* yb = Y + (size_t)b * HH * WW;

  float thin_x[16]; int rc_x[16];
  canny_tile(xb, base_r, base_c, sA, sB, kb, thin_x, rc_x);
  float thin_y[16]; int rc_y[16];
  canny_tile(yb, base_r, base_c, sA, sB, kb, thin_y, rc_y);

  float s = 0.f; int so = 0;
  #pragma unroll
  for (int i = 0; i < 16; ++i) {
    s += fabsf(thin_x[i] - thin_y[i]);
    so += abs(rc_x[i] - rc_y[i]);
  }
  s += 45.f * (float)so;

  // wave reduce (64 lanes), then cross-wave via LDS, one atomic per block
  #pragma unroll
  for (int off = 32; off >= 1; off >>= 1) s += __shfl_down(s, off, 64);
  const int lane = threadIdx.x & 63, wv = threadIdx.x >> 6;
  if (lane == 0) red[wv] = s;
  __syncthreads();
  if (threadIdx.x == 0) {
    float t = red[0] + red[1] + red[2] + red[3];
    atomicAdd(out, t * (1.0f / ((float)HH * (float)WW)));
  }
}

extern "C" void kernel_launch(void* const* d_in, const int* in_sizes, int n_in,
                              void* d_out, int out_size, void* d_ws, size_t ws_size,
                              hipStream_t stream)
{
  const float* X = (const float*)d_in[0];
  const float* Y = (const float*)d_in[1];
  float* out = (float*)d_out;

  hipMemsetAsync(out, 0, (size_t)out_size * sizeof(float), stream);

  // Gaussian 1D weights in double, cast to f32 (matches reference f64->f32 path)
  Blur5 kb;
  {
    double g[5], ssum = 0.0;
    for (int i = 0; i < 5; ++i) { double d = i - 2; g[i] = std::exp(-(d * d) / 2.0); ssum += g[i]; }
    for (int i = 0; i < 5; ++i) kb.w[i] = (float)(g[i] / ssum);
  }

  dim3 grid(64, 16);   // 8x8 tiles of 64x64 per image, 16 batch
  canny_loss_kernel<<<grid, NTHREADS, 0, stream>>>(X, Y, out, kb);
}

// Round 4
// 54.030 us; speedup vs baseline: 2.0105x; 1.0699x over previous
//
#include <hip/hip_runtime.h>
#include <cmath>

#define HH 512
#define WW 512
#define TILE 64
#define S_IMG 72   // staged image stride (72x72, halo 4)
#define S_T  68    // stride for hblur / blurred / mag tiles (272B, 16B-aligned)
#define NT 256

struct Blur5 { float w[5]; };

// packed (dr+1),(dc+1) 2-bit LUTs for the 8 NMS directions
// OFFS = {(0,1),(-1,1),(-1,0),(-1,-1),(0,-1),(1,-1),(1,0),(1,1)}
#define DR_PACK 43265u
#define DC_PACK 36890u

__device__ __forceinline__ float4 ld4(const float* p) {
  return *reinterpret_cast<const float4*>(p);
}
__device__ __forceinline__ void st4(float* p, float4 v) {
  *reinterpret_cast<float4*>(p) = v;
}

// rc = jnp.round((degrees(atan2(gy,gx)) + 180)/45) in [0,8], via comparisons.
// Validated vs reference in R1/R2 (absmax 0.0).
__device__ __forceinline__ int orient_bin(float gx, float gy) {
  const float T1 = 0.41421356237309503f;  // tan(22.5)
  const float T2 = 2.41421356237309503f;  // tan(67.5)
  float a = fabsf(gy), b = fabsf(gx);
  int sx = (int)(__float_as_uint(gx) >> 31);
  int sy = (int)(__float_as_uint(gy) >> 31);
  int rc;
  if (a <= T1 * b)      rc = sx ? (8 - 8 * sy) : 4;
  else if (a >= T2 * b) rc = 6 - 4 * sy;
  else                  rc = sx ? (7 - 6 * sy) : (5 - 2 * sy);
  return rc;
}

// ACC=false: store thin/rc into arrays.  ACC=true: accumulate loss vs arrays.
template<bool ACC>
__device__ __forceinline__ void canny_tile(
    const float* __restrict__ img, int base_r, int base_c,
    float* __restrict__ sA, float* __restrict__ sB, const Blur5& kb,
    float thin[16], int rcv[16], float& sAcc, int& soAcc)
{
  const int tid = threadIdx.x;
  const float k0 = kb.w[0], k1 = kb.w[1], k2 = kb.w[2], k3 = kb.w[3], k4 = kb.w[4];

  // ---- P1: stage 72x72 image tile (halo 4) as float4 groups ----
  // group = 4 consecutive cols; always fully inside or fully outside image.
  for (unsigned g = tid; g < 72u * 18u; g += NT) {
    unsigned r = g / 18u, k = g - r * 18u;
    int gr = base_r + (int)r - 4;
    int gcb = base_c + (int)(k * 4u) - 4;
    float4 v = {0.f, 0.f, 0.f, 0.f};
    if ((unsigned)gr < HH && (unsigned)gcb < WW)
      v = ld4(img + gr * WW + gcb);
    st4(&sA[r * S_IMG + k * 4u], v);
  }
  __syncthreads();

  // ---- P2: horizontal 5-tap blur -> sB [72][68] ----
  for (unsigned g = tid; g < 72u * 17u; g += NT) {
    unsigned r = g / 17u, k = g - r * 17u, c4 = k * 4u;
    const float* p = &sA[r * S_IMG + c4];
    float4 a = ld4(p), b = ld4(p + 4);
    float4 o;
    o.x = k0*a.x + k1*a.y + k2*a.z + k3*a.w + k4*b.x;
    o.y = k0*a.y + k1*a.z + k2*a.w + k3*b.x + k4*b.y;
    o.z = k0*a.z + k1*a.w + k2*b.x + k3*b.y + k4*b.z;
    o.w = k0*a.w + k1*b.x + k2*b.y + k3*b.z + k4*b.w;
    st4(&sB[r * S_T + c4], o);
  }
  __syncthreads();

  // ---- P3: vertical 5-tap blur -> sA [68][68]; zero outside image ----
  for (unsigned g = tid; g < 68u * 17u; g += NT) {
    unsigned r = g / 17u, k = g - r * 17u, c4 = k * 4u;
    const float* p = &sB[r * S_T + c4];
    float4 v0 = ld4(p), v1 = ld4(p + S_T), v2 = ld4(p + 2*S_T),
           v3 = ld4(p + 3*S_T), v4 = ld4(p + 4*S_T);
    float4 o;
    o.x = k0*v0.x + k1*v1.x + k2*v2.x + k3*v3.x + k4*v4.x;
    o.y = k0*v0.y + k1*v1.y + k2*v2.y + k3*v3.y + k4*v4.y;
    o.z = k0*v0.z + k1*v1.z + k2*v2.z + k3*v3.z + k4*v4.z;
    o.w = k0*v0.w + k1*v1.w + k2*v2.w + k3*v3.w + k4*v4.w;
    bool rok = (unsigned)(base_r + (int)r - 2) < HH;
    int gcb = base_c + (int)c4 - 2;
    o.x = (rok && (unsigned)(gcb + 0) < WW) ? o.x : 0.f;
    o.y = (rok && (unsigned)(gcb + 1) < WW) ? o.y : 0.f;
    o.z = (rok && (unsigned)(gcb + 2) < WW) ? o.z : 0.f;
    o.w = (rok && (unsigned)(gcb + 3) < WW) ? o.w : 0.f;
    st4(&sA[r * S_T + c4], o);
  }
  __syncthreads();

  // ---- P4a: sobel magnitude -> sB [66][68]; zero outside image ----
  // (cols 66,67 of each group-16 row are garbage; never read downstream)
  for (unsigned g = tid; g < 66u * 17u; g += NT) {
    unsigned r = g / 17u, k = g - r * 17u, c4 = k * 4u;
    const float* p = &sA[r * S_T + c4];
    float4 a0 = ld4(p),           b0 = ld4(p + 4);
    float4 a1 = ld4(p + S_T),     b1 = ld4(p + S_T + 4);
    float4 a2 = ld4(p + 2*S_T),   b2 = ld4(p + 2*S_T + 4);
    float e0[6] = {a0.x,a0.y,a0.z,a0.w,b0.x,b0.y};
    float e1[6] = {a1.x,a1.y,a1.z,a1.w,b1.x,b1.y};
    float e2[6] = {a2.x,a2.y,a2.z,a2.w,b2.x,b2.y};
    bool rok = (unsigned)(base_r + (int)r - 1) < HH;
    int gcb = base_c + (int)c4 - 1;
    float4 o;
    float* po = &o.x;
    #pragma unroll
    for (int j = 0; j < 4; ++j) {
      float gx = (e0[j+2]-e0[j]) + 2.f*(e1[j+2]-e1[j]) + (e2[j+2]-e2[j]);
      float gy = (e2[j]-e0[j]) + 2.f*(e2[j+1]-e0[j+1]) + (e2[j+2]-e0[j+2]);
      float m = sqrtf(gx*gx + gy*gy + 1e-12f);
      po[j] = (rok && (unsigned)(gcb + j) < WW) ? m : 0.f;
    }
    st4(&sB[r * S_T + c4], o);
  }
  __syncthreads();

  // ---- P4b+P5: orientation bin + NMS over center 64x64, loss fusion ----
  #pragma unroll
  for (int it = 0; it < 4; ++it) {
    unsigned g = tid + it * NT;          // 1024 groups of 4 pixels
    unsigned r = g >> 4, c4 = (g & 15u) * 4u;
    const float* p = &sA[(r + 1) * S_T + c4];   // blurred rows r+1..r+3
    float4 a0 = ld4(p),           b0 = ld4(p + 4);
    float4 a1 = ld4(p + S_T),     b1 = ld4(p + S_T + 4);
    float4 a2 = ld4(p + 2*S_T),   b2 = ld4(p + 2*S_T + 4);
    float e0[8] = {a0.x,a0.y,a0.z,a0.w,b0.x,b0.y,b0.z,b0.w};
    float e1[8] = {a1.x,a1.y,a1.z,a1.w,b1.x,b1.y,b1.z,b1.w};
    float e2[8] = {a2.x,a2.y,a2.z,a2.w,b2.x,b2.y,b2.z,b2.w};
    const float* q = &sB[(r + 1) * S_T + c4];   // mag row r+1
    float4 ma = ld4(q), mb = ld4(q + 4);
    float mc[4] = {ma.y, ma.z, ma.w, mb.x};     // centers cols c4+1..c4+4
    #pragma unroll
    for (int j = 0; j < 4; ++j) {
      // sobel at center pixel (r, c4+j): blurred window cols (c4+j+1)..(c4+j+3)
      float gx = (e0[j+3]-e0[j+1]) + 2.f*(e1[j+3]-e1[j+1]) + (e2[j+3]-e2[j+1]);
      float gy = (e2[j+1]-e0[j+1]) + 2.f*(e2[j+2]-e0[j+2]) + (e2[j+3]-e0[j+3]);
      int rc = orient_bin(gx, gy);
      int ip = rc & 7;
      int dr = (int)((DR_PACK >> (2 * ip)) & 3u) - 1;
      int dc = (int)((DC_PACK >> (2 * ip)) & 3u) - 1;
      int ci = (int)((r + 1) * S_T + c4 + 1 + j);
      float n1 = sB[ci + dr * S_T + dc];
      float n2 = sB[ci - dr * S_T - dc];
      float th = (fminf(mc[j] - n1, mc[j] - n2) > 0.f) ? mc[j] : 0.f;
      int idx = it * 4 + j;
      if (ACC) {
        sAcc += fabsf(thin[idx] - th);
        soAcc += abs(rcv[idx] - rc);
      } else {
        thin[idx] = th;
        rcv[idx] = rc;
      }
    }
  }
  __syncthreads();  // protect sA/sB before reuse
}

__global__ void __launch_bounds__(NT)
canny_loss_kernel(const float* __restrict__ X, const float* __restrict__ Y,
                  float* __restrict__ out, Blur5 kb)
{
  __shared__ float sA[S_IMG * S_IMG];
  __shared__ float sB[S_IMG * S_T];
  __shared__ float red[NT / 64];

  const int b = blockIdx.y;
  const int base_r = (int)(blockIdx.x >> 3) * TILE;
  const int base_c = (int)(blockIdx.x & 7) * TILE;
  const float* xb = X + (size_t)b * HH * WW;
  const float* yb = Y + (size_t)b * HH * WW;

  float thin_x[16]; int rc_x[16];
  float s = 0.f; int so = 0;
  canny_tile<false>(xb, base_r, base_c, sA, sB, kb, thin_x, rc_x, s, so);
  canny_tile<true >(yb, base_r, base_c, sA, sB, kb, thin_x, rc_x, s, so);
  s += 45.f * (float)so;

  // wave reduce (64 lanes), then cross-wave via LDS, one atomic per block
  #pragma unroll
  for (int off = 32; off >= 1; off >>= 1) s += __shfl_down(s, off, 64);
  const int lane = threadIdx.x & 63, wv = threadIdx.x >> 6;
  if (lane == 0) red[wv] = s;
  __syncthreads();
  if (threadIdx.x == 0) {
    float t = red[0] + red[1] + red[2] + red[3];
    atomicAdd(out, t * (1.0f / ((float)HH * (float)WW)));
  }
}

extern "C" void kernel_launch(void* const* d_in, const int* in_sizes, int n_in,
                              void* d_out, int out_size, void* d_ws, size_t ws_size,
                              hipStream_t stream)
{
  const float* X = (const float*)d_in[0];
  const float* Y = (const float*)d_in[1];
  float* out = (float*)d_out;

  hipMemsetAsync(out, 0, (size_t)out_size * sizeof(float), stream);

  // Gaussian 1D weights in double, cast to f32 (matches reference f64->f32 path)
  Blur5 kb;
  {
    double g[5], ssum = 0.0;
    for (int i = 0; i < 5; ++i) { double d = i - 2; g[i] = std::exp(-(d * d) / 2.0); ssum += g[i]; }
    for (int i = 0; i < 5; ++i) kb.w[i] = (float)(g[i] / ssum);
  }

  dim3 grid(64, 16);   // 8x8 tiles of 64x64 per image, 16 batch
  canny_loss_kernel<<<grid, NT, 0, stream>>>(X, Y, out, kb);
}